// Round 4
// baseline (196.404 us; speedup 1.0000x reference)
//
#include <hip/hip_runtime.h>
#include <hip/hip_bf16.h>

// CLIP loss: B=8192, D=1024, temp=0.5.
// loss = mean_i [ 0.5*(log sum_j exp(s_ij) + log sum_j exp(s_ji)) - s_ii ],
// s = (zi_n @ zj_n^T) * 2.  |s| <= 2 -> exp safe, no max trick.
//
// GEMM: m201-style 8-phase schedule. BM=BN=256, BK=64 (2 K-halves of 32),
// 512 thr = 8 waves (2M x 4N), per-wave 128x64 output, acc[8][4].
// R4 change: panel row stride padded 1024 -> 1056 shorts (2112 B = 33*64)
// to break power-of-2 L2 channel aliasing on the 64B-strided staging reads.
//
// ws: [0,16.5M) zi_bf LD=1056 (x2 temp folded), [16.5M,33M) zj_bf,
//     [33M,+1M) rp[32][8192], [34M,+1M) cp[32][8192], [35M,+32K) dg[8192],
//     then part[32].

#define LD 1056   // padded leading dim (shorts); 2112 B = 33*64

using short8 = __attribute__((ext_vector_type(8))) short;
using f32x4  = __attribute__((ext_vector_type(4))) float;

__device__ __forceinline__ unsigned short f2bf(float f) {
    unsigned int u = __float_as_uint(f);
    unsigned int r = (u + 0x7FFFu + ((u >> 16) & 1u)) >> 16;
    return (unsigned short)r;
}

__device__ __forceinline__ void async16(const unsigned short* g, unsigned short* l) {
    __builtin_amdgcn_global_load_lds(
        (const __attribute__((address_space(1))) void*)g,
        (__attribute__((address_space(3))) void*)l, 16, 0, 0);
}

// ---- kernel 1: row-normalize fp32 -> bf16 (padded LD), extra scale folded ----
__global__ __launch_bounds__(256) void clip_norm_k(const float* __restrict__ in,
                                                   unsigned short* __restrict__ out,
                                                   float extra) {
    int row = blockIdx.x;
    const float4* ip = reinterpret_cast<const float4*>(in + (size_t)row * 1024);
    float4 v = ip[threadIdx.x];
    float ss = v.x * v.x + v.y * v.y + v.z * v.z + v.w * v.w;
    #pragma unroll
    for (int o = 1; o < 64; o <<= 1) ss += __shfl_xor(ss, o);
    __shared__ float sb[4];
    if ((threadIdx.x & 63) == 0) sb[threadIdx.x >> 6] = ss;
    __syncthreads();
    float tot = sb[0] + sb[1] + sb[2] + sb[3];
    float scl = extra / fmaxf(sqrtf(tot), 1e-12f);
    ushort4 o4;
    o4.x = f2bf(v.x * scl);
    o4.y = f2bf(v.y * scl);
    o4.z = f2bf(v.z * scl);
    o4.w = f2bf(v.w * scl);
    *reinterpret_cast<ushort4*>(out + (size_t)row * LD + threadIdx.x * 4) = o4;
}

// chunk = [256][32] shorts (16 KB). 2 sweeps x 512 threads x 16B.
// LDS dest linear (wave-uniform base + lane*16); source pre-swizzled.
__device__ __forceinline__ void stage_chunk(const unsigned short* G,
                                            unsigned short* chunk,
                                            int kofs, int tid) {
    #pragma unroll
    for (int s = 0; s < 2; ++s) {
        int idx = s * 512 + tid;
        int row = idx >> 2;
        int clog = (idx & 3) ^ ((row >> 1) & 3);
        async16(G + (size_t)row * LD + kofs + clog * 8, chunk + idx * 8);
    }
}

__device__ __forceinline__ short8 ldfrag(const unsigned short* chunk, int row, int lhi) {
    int cphys = lhi ^ ((row >> 1) & 3);
    return *reinterpret_cast<const short8*>(chunk + row * 32 + cphys * 8);
}

__global__ __launch_bounds__(512, 2) void clip_gemm_k(
    const unsigned short* __restrict__ A,   // zi_bf [8192][LD]
    const unsigned short* __restrict__ Bm,  // zj_bf [8192][LD]
    float* __restrict__ rp, float* __restrict__ cp, float* __restrict__ dg) {
    __shared__ unsigned short sh[65536];     // A: [0,32768) B: [32768,65536)
    __shared__ float rbuf[4][256];
    __shared__ float cbuf[2][256];

    // XCD stripe swizzle: 1024 blocks, XCD c gets bj in [4c,4c+4), all bi.
    const int c_x = blockIdx.x & 7, q = blockIdx.x >> 3;
    const int bj = c_x * 4 + (q & 3);        // 0..31
    const int bi = q >> 2;                   // 0..31
    const int tid = threadIdx.x;
    const int l = tid & 63, w = tid >> 6;
    const int wm = w >> 2, wn = w & 3;       // 2M x 4N wave grid
    const int lhi = l >> 4, llo = l & 15;

    f32x4 acc[8][4] = {};

    const unsigned short* Ag = A + (size_t)(bi * 256) * LD;
    const unsigned short* Bg = Bm + (size_t)(bj * 256) * LD;

    unsigned short* As_ = sh;            // [db][kh][256][32]
    unsigned short* Bs_ = sh + 32768;

    // prologue: t0.A0,t0.B0,t0.A1,t0.B1,t1.A0,t1.B0 then vmcnt(4)=t0 landed
    stage_chunk(Ag, As_ + 0 * 8192, 0, tid);
    stage_chunk(Bg, Bs_ + 0 * 8192, 0, tid);
    stage_chunk(Ag, As_ + 1 * 8192, 32, tid);
    stage_chunk(Bg, Bs_ + 1 * 8192, 32, tid);
    stage_chunk(Ag, As_ + 2 * 8192, 64, tid);
    stage_chunk(Bg, Bs_ + 2 * 8192, 64, tid);
    asm volatile("s_waitcnt vmcnt(4)" ::: "memory");
    __builtin_amdgcn_s_barrier();
    __builtin_amdgcn_sched_barrier(0);

    short8 af[4], bf_[4];

#define MFMA_Q(MH)                                                        \
    __builtin_amdgcn_s_setprio(1);                                        \
    _Pragma("unroll") for (int m = 0; m < 4; ++m)                         \
    _Pragma("unroll") for (int n = 0; n < 4; ++n)                         \
        acc[(MH)*4+m][n] = __builtin_amdgcn_mfma_f32_16x16x32_bf16(       \
            af[m], bf_[n], acc[(MH)*4+m][n], 0, 0, 0);                    \
    __builtin_amdgcn_s_setprio(0);                                        \
    __builtin_amdgcn_sched_barrier(0);

    for (int t = 0; t < 16; ++t) {
        const int db = t & 1;
        const unsigned short* Ak0 = As_ + (db * 2 + 0) * 8192;
        const unsigned short* Ak1 = As_ + (db * 2 + 1) * 8192;
        const unsigned short* Bk0 = Bs_ + (db * 2 + 0) * 8192;
        const unsigned short* Bk1 = Bs_ + (db * 2 + 1) * 8192;
        unsigned short* nA1 = As_ + (((t + 1) & 1) * 2 + 1) * 8192;  // (t+1) khalf1
        unsigned short* nB1 = Bs_ + (((t + 1) & 1) * 2 + 1) * 8192;
        unsigned short* nA0 = As_ + (db * 2 + 0) * 8192;             // (t+2) khalf0
        unsigned short* nB0 = Bs_ + (db * 2 + 0) * 8192;

        // ---- phase 0: kk0, mh0 (reads B kk0 too); stage (t+1).A1 ----
        #pragma unroll
        for (int m = 0; m < 4; ++m) af[m] = ldfrag(Ak0, wm * 128 + m * 16 + llo, lhi);
        #pragma unroll
        for (int n = 0; n < 4; ++n) bf_[n] = ldfrag(Bk0, wn * 64 + n * 16 + llo, lhi);
        if (t <= 14) stage_chunk(Ag, nA1, (t + 1) * 64 + 32, tid);
        __builtin_amdgcn_s_barrier();
        asm volatile("s_waitcnt lgkmcnt(0)" ::: "memory");
        __builtin_amdgcn_sched_barrier(0);
        MFMA_Q(0)
        __builtin_amdgcn_s_barrier();

        // ---- phase 1: kk0, mh1 (B reused); stage (t+1).B1 ----
        #pragma unroll
        for (int m = 0; m < 4; ++m) af[m] = ldfrag(Ak0, wm * 128 + 64 + m * 16 + llo, lhi);
        if (t <= 14) stage_chunk(Bg, nB1, (t + 1) * 64 + 32, tid);
        __builtin_amdgcn_s_barrier();
        asm volatile("s_waitcnt lgkmcnt(0)" ::: "memory");
        __builtin_amdgcn_sched_barrier(0);
        MFMA_Q(1)
        __builtin_amdgcn_s_barrier();

        // ---- phase 2: kk1, mh0 (reads B kk1); stage (t+2).A0 ----
        #pragma unroll
        for (int m = 0; m < 4; ++m) af[m] = ldfrag(Ak1, wm * 128 + m * 16 + llo, lhi);
        #pragma unroll
        for (int n = 0; n < 4; ++n) bf_[n] = ldfrag(Bk1, wn * 64 + n * 16 + llo, lhi);
        if (t <= 13) stage_chunk(Ag, nA0, (t + 2) * 64, tid);
        __builtin_amdgcn_s_barrier();
        asm volatile("s_waitcnt lgkmcnt(0)" ::: "memory");
        __builtin_amdgcn_sched_barrier(0);
        MFMA_Q(0)
        __builtin_amdgcn_s_barrier();

        // ---- phase 3: kk1, mh1 (B reused); stage (t+2).B0; boundary wait ----
        #pragma unroll
        for (int m = 0; m < 4; ++m) af[m] = ldfrag(Ak1, wm * 128 + 64 + m * 16 + llo, lhi);
        if (t <= 13) stage_chunk(Bg, nB0, (t + 2) * 64, tid);
        __builtin_amdgcn_s_barrier();
        asm volatile("s_waitcnt lgkmcnt(0)" ::: "memory");
        __builtin_amdgcn_sched_barrier(0);
        MFMA_Q(1)
        if (t <= 13)      asm volatile("s_waitcnt vmcnt(4)" ::: "memory");
        else if (t == 14) asm volatile("s_waitcnt vmcnt(0)" ::: "memory");
        __builtin_amdgcn_s_barrier();
    }
#undef MFMA_Q

    // ---- epilogue ----
    // C frag layout: col = llo, row = lhi*4 + reg.
    if (bi == bj) {
        #pragma unroll
        for (int m = 0; m < 8; ++m)
            #pragma unroll
            for (int n = 0; n < 4; ++n)
                #pragma unroll
                for (int r = 0; r < 4; ++r) {
                    int lrow = wm * 128 + m * 16 + lhi * 4 + r;
                    int lcol = wn * 64 + n * 16 + llo;
                    if (lrow == lcol) dg[bi * 256 + lrow] = acc[m][n][r];
                }
    }

    #pragma unroll
    for (int m = 0; m < 8; ++m)
        #pragma unroll
        for (int n = 0; n < 4; ++n)
            #pragma unroll
            for (int r = 0; r < 4; ++r)
                acc[m][n][r] = exp2f(acc[m][n][r] * 1.44269504f);

    // row sums (this wave's 64 cols); reduce over llo then across wn via LDS
    #pragma unroll
    for (int m = 0; m < 8; ++m) {
        #pragma unroll
        for (int r = 0; r < 4; ++r) {
            float v = acc[m][0][r] + acc[m][1][r] + acc[m][2][r] + acc[m][3][r];
            v += __shfl_xor(v, 1);
            v += __shfl_xor(v, 2);
            v += __shfl_xor(v, 4);
            v += __shfl_xor(v, 8);
            if (llo == 0) rbuf[wn][wm * 128 + m * 16 + lhi * 4 + r] = v;
        }
    }
    // col sums (this wave's 128 rows); reduce over lhi then across wm via LDS
    #pragma unroll
    for (int n = 0; n < 4; ++n) {
        float v = 0.f;
        #pragma unroll
        for (int m = 0; m < 8; ++m)
            v += acc[m][n][0] + acc[m][n][1] + acc[m][n][2] + acc[m][n][3];
        v += __shfl_xor(v, 16);
        v += __shfl_xor(v, 32);
        if (lhi == 0) cbuf[wm][wn * 64 + n * 16 + llo] = v;
    }
    __syncthreads();
    if (tid < 256) {
        rp[(size_t)bj * 8192 + bi * 256 + tid] =
            rbuf[0][tid] + rbuf[1][tid] + rbuf[2][tid] + rbuf[3][tid];
        cp[(size_t)bi * 8192 + bj * 256 + tid] = cbuf[0][tid] + cbuf[1][tid];
    }
}

// ---- per-row logs, block partial sums ----
__global__ __launch_bounds__(256) void clip_fin1_k(const float* __restrict__ rp,
                                                   const float* __restrict__ cp,
                                                   const float* __restrict__ dg,
                                                   float* __restrict__ part) {
    int i = blockIdx.x * 256 + threadIdx.x;
    float rs = 0.f, cs = 0.f;
    #pragma unroll 8
    for (int b = 0; b < 32; ++b) rs += rp[(size_t)b * 8192 + i];
    #pragma unroll 8
    for (int b = 0; b < 32; ++b) cs += cp[(size_t)b * 8192 + i];
    float c = 0.5f * (logf(rs) + logf(cs)) - dg[i];
    #pragma unroll
    for (int o = 1; o < 64; o <<= 1) c += __shfl_xor(c, o);
    __shared__ float sb[4];
    if ((threadIdx.x & 63) == 0) sb[threadIdx.x >> 6] = c;
    __syncthreads();
    if (threadIdx.x == 0) part[blockIdx.x] = sb[0] + sb[1] + sb[2] + sb[3];
}

__global__ void clip_fin2_k(const float* __restrict__ part, float* __restrict__ out) {
    float v = (threadIdx.x < 32) ? part[threadIdx.x] : 0.f;
    #pragma unroll
    for (int o = 1; o < 64; o <<= 1) v += __shfl_xor(v, o);
    if (threadIdx.x == 0) out[0] = v * (1.f / 8192.f);
}

extern "C" void kernel_launch(void* const* d_in, const int* in_sizes, int n_in,
                              void* d_out, int out_size, void* d_ws, size_t ws_size,
                              hipStream_t stream) {
    const float* zi = (const float*)d_in[0];
    const float* zj = (const float*)d_in[1];
    float* out = (float*)d_out;
    char* ws = (char*)d_ws;

    // padded panels: 8192 * 1056 shorts = 17,301,504 B each
    unsigned short* zib = (unsigned short*)(ws);
    unsigned short* zjb = (unsigned short*)(ws + (size_t)17301504);
    float* rp   = (float*)(ws + (size_t)33 * 1024 * 1024);
    float* cp   = (float*)(ws + (size_t)34 * 1024 * 1024);
    float* dg   = (float*)(ws + (size_t)35 * 1024 * 1024);
    float* part = (float*)(ws + (size_t)35 * 1024 * 1024 + 32768);

    clip_norm_k<<<8192, 256, 0, stream>>>(zi, zib, 2.0f);   // temp x2 folded into zi
    clip_norm_k<<<8192, 256, 0, stream>>>(zj, zjb, 1.0f);
    clip_gemm_k<<<1024, 512, 0, stream>>>(zib, zjb, rp, cp, dg);
    clip_fin1_k<<<32, 256, 0, stream>>>(rp, cp, dg, part);
    clip_fin2_k<<<1, 64, 0, stream>>>(part, out);
}

// Round 5
// 179.776 us; speedup vs baseline: 1.0925x; 1.0925x over previous
//
#include <hip/hip_runtime.h>
#include <hip/hip_bf16.h>

// CLIP loss: B=8192, D=1024, temp=0.5.
// loss = mean_i [ 0.5*(log sum_j exp(s_ij) + log sum_j exp(s_ji)) - s_ii ],
// s = (zi_n @ zj_n^T) * 2.  |s| <= 2 -> exp safe, no max trick.
//
// R5: un-pinned schedule. BM=BN=256, BK=64, 8 waves (2M x 4N), double-buffer
// [256][64]-short chunks (A+B = 64 KB/buf, 128 KB total). Per K-tile ONE open
// region: 24 ds_read_b128 + 64 MFMA with NO internal fences (compiler emits
// counted lgkmcnt and interleaves LDS/MFMA pipes), then lgkm(0)+barrier,
// stage t+2 (8 gload_lds), vmcnt(8) (t+1 landed, issued a tile ago), barrier.
// Swizzle: 16B-chunk cphys = clog ^ (row&7) both sides -> 2 lanes/bank (free).
//
// ws: [0,16M) zi_bf (x2 temp folded), [16M,32M) zj_bf, [32M,+1M) rp[32][8192],
//     [34M,+1M) cp[32][8192], [36M,+32K) dg[8192], then part[32].

using short8 = __attribute__((ext_vector_type(8))) short;
using f32x4  = __attribute__((ext_vector_type(4))) float;

__device__ __forceinline__ unsigned short f2bf(float f) {
    unsigned int u = __float_as_uint(f);
    unsigned int r = (u + 0x7FFFu + ((u >> 16) & 1u)) >> 16;
    return (unsigned short)r;
}

__device__ __forceinline__ void async16(const unsigned short* g, unsigned short* l) {
    __builtin_amdgcn_global_load_lds(
        (const __attribute__((address_space(1))) void*)g,
        (__attribute__((address_space(3))) void*)l, 16, 0, 0);
}

// ---- kernel 1: row-normalize fp32 -> bf16, extra scale folded ----
__global__ __launch_bounds__(256) void clip_norm_k(const float* __restrict__ in,
                                                   unsigned short* __restrict__ out,
                                                   float extra) {
    int row = blockIdx.x;
    const float4* ip = reinterpret_cast<const float4*>(in + (size_t)row * 1024);
    float4 v = ip[threadIdx.x];
    float ss = v.x * v.x + v.y * v.y + v.z * v.z + v.w * v.w;
    #pragma unroll
    for (int o = 1; o < 64; o <<= 1) ss += __shfl_xor(ss, o);
    __shared__ float sb[4];
    if ((threadIdx.x & 63) == 0) sb[threadIdx.x >> 6] = ss;
    __syncthreads();
    float tot = sb[0] + sb[1] + sb[2] + sb[3];
    float scl = extra / fmaxf(sqrtf(tot), 1e-12f);
    ushort4 o4;
    o4.x = f2bf(v.x * scl);
    o4.y = f2bf(v.y * scl);
    o4.z = f2bf(v.z * scl);
    o4.w = f2bf(v.w * scl);
    *reinterpret_cast<ushort4*>(out + (size_t)row * 1024 + threadIdx.x * 4) = o4;
}

// Stage one [256][64]-short tile chunk (32 KB): 4 sweeps x 512 thr x 16B.
// LDS dest linear; global source pre-swizzled (involution c ^ (row&7)).
__device__ __forceinline__ void stage_tile(const unsigned short* G,
                                           unsigned short* buf,
                                           int kofs, int tid) {
    #pragma unroll
    for (int s = 0; s < 4; ++s) {
        int idx = s * 512 + tid;
        int row = idx >> 3;
        int clog = (idx & 7) ^ (row & 7);
        async16(G + (size_t)row * 1024 + kofs + clog * 8, buf + idx * 8);
    }
}

__device__ __forceinline__ short8 ldfrag(const unsigned short* buf, int row, int c) {
    int cphys = c ^ (row & 7);
    return *reinterpret_cast<const short8*>(buf + row * 64 + cphys * 8);
}

__global__ __launch_bounds__(512, 2) void clip_gemm_k(
    const unsigned short* __restrict__ A,   // zi_bf [8192][1024]
    const unsigned short* __restrict__ Bm,  // zj_bf [8192][1024]
    float* __restrict__ rp, float* __restrict__ cp, float* __restrict__ dg) {
    __shared__ unsigned short sh[131072 / 2];   // 2 bufs x (A 16384 + B 16384) shorts
    __shared__ float rbuf[4][256];
    __shared__ float cbuf[2][256];

    // XCD stripe swizzle: 1024 blocks, XCD c gets bj in [4c,4c+4), all bi.
    const int c_x = blockIdx.x & 7, q = blockIdx.x >> 3;
    const int bj = c_x * 4 + (q & 3);        // 0..31
    const int bi = q >> 2;                   // 0..31
    const int tid = threadIdx.x;
    const int l = tid & 63, w = tid >> 6;
    const int wm = w >> 2, wn = w & 3;       // 2M x 4N wave grid
    const int lhi = l >> 4, llo = l & 15;

    f32x4 acc[8][4] = {};

    const unsigned short* Ag = A + (size_t)(bi * 256) * 1024;
    const unsigned short* Bg = Bm + (size_t)(bj * 256) * 1024;

    unsigned short* A0 = sh;                 // buf0: A [256][64], B [256][64]
    unsigned short* B0 = sh + 16384;
    unsigned short* A1 = sh + 32768;
    unsigned short* B1 = sh + 49152;

    // prologue: stage tiles 0 and 1; wait tile 0 (vmcnt leaves tile1's 8)
    stage_tile(Ag, A0, 0, tid);
    stage_tile(Bg, B0, 0, tid);
    stage_tile(Ag, A1, 64, tid);
    stage_tile(Bg, B1, 64, tid);
    asm volatile("s_waitcnt vmcnt(8)" ::: "memory");
    __builtin_amdgcn_s_barrier();
    __builtin_amdgcn_sched_barrier(0);

    for (int t = 0; t < 16; ++t) {
        const unsigned short* Ac = (t & 1) ? A1 : A0;
        const unsigned short* Bc = (t & 1) ? B1 : B0;
        unsigned short* Asg = (t & 1) ? A1 : A0;   // stage t+2 into same-parity buf
        unsigned short* Bsg = (t & 1) ? B1 : B0;

        // ---- open compute region: no fences, compiler pipelines ----
        #pragma unroll
        for (int kk = 0; kk < 2; ++kk) {
            short8 af[8], bf_[4];
            #pragma unroll
            for (int m = 0; m < 8; ++m)
                af[m] = ldfrag(Ac, wm * 128 + m * 16 + llo, kk * 4 + lhi);
            #pragma unroll
            for (int n = 0; n < 4; ++n)
                bf_[n] = ldfrag(Bc, wn * 64 + n * 16 + llo, kk * 4 + lhi);
            #pragma unroll
            for (int m = 0; m < 8; ++m)
                #pragma unroll
                for (int n = 0; n < 4; ++n)
                    acc[m][n] = __builtin_amdgcn_mfma_f32_16x16x32_bf16(
                        af[m], bf_[n], acc[m][n], 0, 0, 0);
        }

        // my reads of buf[cur] are done -> signal, then restage it
        asm volatile("s_waitcnt lgkmcnt(0)" ::: "memory");
        __builtin_amdgcn_s_barrier();
        if (t <= 13) {
            stage_tile(Ag, Asg, (t + 2) * 64, tid);
            stage_tile(Bg, Bsg, (t + 2) * 64, tid);
            asm volatile("s_waitcnt vmcnt(8)" ::: "memory");   // t+1 landed
        } else if (t == 14) {
            asm volatile("s_waitcnt vmcnt(0)" ::: "memory");   // t=15 landed
        }
        if (t <= 14) {
            __builtin_amdgcn_s_barrier();
            __builtin_amdgcn_sched_barrier(0);
        }
    }

    // ---- epilogue (verified R3/R4) ----
    // C frag layout: col = llo, row = lhi*4 + reg.
    if (bi == bj) {
        #pragma unroll
        for (int m = 0; m < 8; ++m)
            #pragma unroll
            for (int n = 0; n < 4; ++n)
                #pragma unroll
                for (int r = 0; r < 4; ++r) {
                    int lrow = wm * 128 + m * 16 + lhi * 4 + r;
                    int lcol = wn * 64 + n * 16 + llo;
                    if (lrow == lcol) dg[bi * 256 + lrow] = acc[m][n][r];
                }
    }

    #pragma unroll
    for (int m = 0; m < 8; ++m)
        #pragma unroll
        for (int n = 0; n < 4; ++n)
            #pragma unroll
            for (int r = 0; r < 4; ++r)
                acc[m][n][r] = exp2f(acc[m][n][r] * 1.44269504f);

    // row sums (this wave's 64 cols); reduce over llo then across wn via LDS
    #pragma unroll
    for (int m = 0; m < 8; ++m) {
        #pragma unroll
        for (int r = 0; r < 4; ++r) {
            float v = acc[m][0][r] + acc[m][1][r] + acc[m][2][r] + acc[m][3][r];
            v += __shfl_xor(v, 1);
            v += __shfl_xor(v, 2);
            v += __shfl_xor(v, 4);
            v += __shfl_xor(v, 8);
            if (llo == 0) rbuf[wn][wm * 128 + m * 16 + lhi * 4 + r] = v;
        }
    }
    // col sums (this wave's 128 rows); reduce over lhi then across wm via LDS
    #pragma unroll
    for (int n = 0; n < 4; ++n) {
        float v = 0.f;
        #pragma unroll
        for (int m = 0; m < 8; ++m)
            v += acc[m][n][0] + acc[m][n][1] + acc[m][n][2] + acc[m][n][3];
        v += __shfl_xor(v, 16);
        v += __shfl_xor(v, 32);
        if (lhi == 0) cbuf[wm][wn * 64 + n * 16 + llo] = v;
    }
    __syncthreads();
    if (tid < 256) {
        rp[(size_t)bj * 8192 + bi * 256 + tid] =
            rbuf[0][tid] + rbuf[1][tid] + rbuf[2][tid] + rbuf[3][tid];
        cp[(size_t)bi * 8192 + bj * 256 + tid] = cbuf[0][tid] + cbuf[1][tid];
    }
}

// ---- per-row logs, block partial sums ----
__global__ __launch_bounds__(256) void clip_fin1_k(const float* __restrict__ rp,
                                                   const float* __restrict__ cp,
                                                   const float* __restrict__ dg,
                                                   float* __restrict__ part) {
    int i = blockIdx.x * 256 + threadIdx.x;
    float rs = 0.f, cs = 0.f;
    #pragma unroll 8
    for (int b = 0; b < 32; ++b) rs += rp[(size_t)b * 8192 + i];
    #pragma unroll 8
    for (int b = 0; b < 32; ++b) cs += cp[(size_t)b * 8192 + i];
    float c = 0.5f * (logf(rs) + logf(cs)) - dg[i];
    #pragma unroll
    for (int o = 1; o < 64; o <<= 1) c += __shfl_xor(c, o);
    __shared__ float sb[4];
    if ((threadIdx.x & 63) == 0) sb[threadIdx.x >> 6] = c;
    __syncthreads();
    if (threadIdx.x == 0) part[blockIdx.x] = sb[0] + sb[1] + sb[2] + sb[3];
}

__global__ void clip_fin2_k(const float* __restrict__ part, float* __restrict__ out) {
    float v = (threadIdx.x < 32) ? part[threadIdx.x] : 0.f;
    #pragma unroll
    for (int o = 1; o < 64; o <<= 1) v += __shfl_xor(v, o);
    if (threadIdx.x == 0) out[0] = v * (1.f / 8192.f);
}

extern "C" void kernel_launch(void* const* d_in, const int* in_sizes, int n_in,
                              void* d_out, int out_size, void* d_ws, size_t ws_size,
                              hipStream_t stream) {
    const float* zi = (const float*)d_in[0];
    const float* zj = (const float*)d_in[1];
    float* out = (float*)d_out;
    char* ws = (char*)d_ws;

    unsigned short* zib = (unsigned short*)(ws);
    unsigned short* zjb = (unsigned short*)(ws + (size_t)16 * 1024 * 1024);
    float* rp   = (float*)(ws + (size_t)32 * 1024 * 1024);
    float* cp   = (float*)(ws + (size_t)34 * 1024 * 1024);
    float* dg   = (float*)(ws + (size_t)36 * 1024 * 1024);
    float* part = (float*)(ws + (size_t)36 * 1024 * 1024 + 32768);

    clip_norm_k<<<8192, 256, 0, stream>>>(zi, zib, 2.0f);   // temp x2 folded into zi
    clip_norm_k<<<8192, 256, 0, stream>>>(zj, zjb, 1.0f);
    clip_gemm_k<<<1024, 512, 0, stream>>>(zib, zjb, rp, cp, dg);
    clip_fin1_k<<<32, 256, 0, stream>>>(rp, cp, dg, part);
    clip_fin2_k<<<1, 64, 0, stream>>>(part, out);
}